// Round 4
// baseline (220.047 us; speedup 1.0000x reference)
//
#include <hip/hip_runtime.h>
#include <hip/hip_bf16.h>

typedef __attribute__((ext_vector_type(8))) short short8;
typedef __attribute__((ext_vector_type(4))) float floatx4;
typedef __attribute__((ext_vector_type(4))) float float4v;
typedef __attribute__((ext_vector_type(4))) unsigned short ushort4v;

#define S_LEN 2048
#define D_MODEL 1024
#define HD 64
#define HQ 16
#define HKV 4
#define QK_PRESCALE 0.18033688011112042f   // 0.125 * log2(e) -> softmax in exp2 domain

__device__ __forceinline__ unsigned short f2bf(float f) {
    unsigned int u = __builtin_bit_cast(unsigned int, f);
    u += 0x7fffu + ((u >> 16) & 1u);   // RNE
    return (unsigned short)(u >> 16);
}

__device__ __forceinline__ unsigned int cvt_pk_bf16(float lo, float hi) {
    unsigned int r;
    asm volatile("v_cvt_pk_bf16_f32 %0, %1, %2" : "=v"(r) : "v"(lo), "v"(hi));
    return r;
}

__device__ __forceinline__ float exp2_hw(float x) {
    float r;
    asm("v_exp_f32 %0, %1" : "=v"(r) : "v"(x));
    return r;
}

__device__ __forceinline__ void gload16(const unsigned short* g, unsigned short* l) {
    __builtin_amdgcn_global_load_lds(
        (const __attribute__((address_space(1))) void*)g,
        (__attribute__((address_space(3))) void*)l, 16, 0, 0);
}

// ---------------- f32 -> bf16 converts ----------------
__global__ void cvt_f32_bf16(const float* __restrict__ in, unsigned short* __restrict__ out, int n) {
    int i = (blockIdx.x * blockDim.x + threadIdx.x) * 4;
    int stride = gridDim.x * blockDim.x * 4;
    for (; i < n; i += stride) {
        float4v v = *(const float4v*)(in + i);
        ushort4v o;
        o.x = f2bf(v.x); o.y = f2bf(v.y); o.z = f2bf(v.z); o.w = f2bf(v.w);
        *(ushort4v*)(out + i) = o;
    }
}

// dst: [wq 1M][wk 256k][wv 256k][wo 1M] contiguous bf16 (2.5M elems)
__global__ void cvt_weights(const float* __restrict__ wq, const float* __restrict__ wk,
                            const float* __restrict__ wv, const float* __restrict__ wo,
                            unsigned short* __restrict__ dst) {
    int i = (blockIdx.x * blockDim.x + threadIdx.x) * 4;
    const float* src; int off;
    if (i < 1048576)      { src = wq; off = i; }
    else if (i < 1310720) { src = wk; off = i - 1048576; }
    else if (i < 1572864) { src = wv; off = i - 1310720; }
    else                  { src = wo; off = i - 1572864; }
    float4v v = *(const float4v*)(src + off);
    ushort4v o;
    o.x = f2bf(v.x); o.y = f2bf(v.y); o.z = f2bf(v.z); o.w = f2bf(v.w);
    *(ushort4v*)(dst + i) = o;
}

// ---------------- GEMM 128x128, BK=64, global_load_lds + XOR swizzle ----------
// C[M,N] = A[M,K] * W[N,K]^T, bf16 MFMA, f32 accum.
// EPI 0: f32 store to C [M x D_MODEL]
// EPI 1: fused QKV epilogue (block-uniform by col0):
//        col0 <1024 -> Q RoPE bf16 (pre-scaled by QK_PRESCALE) ; <1280 -> K RoPE bf16 ;
//        else V transposed bf16
template<int EPI>
__global__ __launch_bounds__(256) void gemm128(
    const unsigned short* __restrict__ A, const unsigned short* __restrict__ W,
    float* __restrict__ C,
    unsigned short* __restrict__ Qb, unsigned short* __restrict__ Kb, unsigned short* __restrict__ Vtb,
    const float* __restrict__ fcos, const float* __restrict__ fsin,
    int K, int N)
{
    __shared__ __align__(16) unsigned short Asm[128 * 64];
    __shared__ __align__(16) unsigned short Bsm[128 * 64];

    const int tid  = threadIdx.x;
    const int lane = tid & 63;
    const int w    = tid >> 6;
    const int wr   = w >> 1, wc = w & 1;
    const int l15  = lane & 15, lhi = lane >> 4;
    const int row0 = blockIdx.x * 128;
    const int col0 = blockIdx.y * 128;

    const int r_in = tid >> 3;           // 0..31
    const int sp   = tid & 7;
    const int sl   = sp ^ (r_in & 7);    // inverse-swizzled source slot

    floatx4 acc[4][4] = {};

    for (int k0 = 0; k0 < K; k0 += 64) {
        #pragma unroll
        for (int i = 0; i < 4; i++) {
            const int r = i * 32 + r_in;
            gload16(A + (size_t)(row0 + r) * K + k0 + sl * 8, Asm + i * 2048 + w * 512);
            gload16(W + (size_t)(col0 + r) * K + k0 + sl * 8, Bsm + i * 2048 + w * 512);
        }
        __syncthreads();

        short8 af[4][2], bfr[4][2];
        const int rx = l15 & 7;
        #pragma unroll
        for (int mi = 0; mi < 4; mi++) {
            const int rowa = wr * 64 + mi * 16 + l15;
            const int rowb = wc * 64 + mi * 16 + l15;
            #pragma unroll
            for (int ks = 0; ks < 2; ks++) {
                const int slot = (ks * 4 + lhi) ^ rx;
                af[mi][ks]  = *(const short8*)&Asm[rowa * 64 + slot * 8];
                bfr[mi][ks] = *(const short8*)&Bsm[rowb * 64 + slot * 8];
            }
        }

        __builtin_amdgcn_s_setprio(1);
        #pragma unroll
        for (int mi = 0; mi < 4; mi++)
        #pragma unroll
        for (int ni = 0; ni < 4; ni++) {
            acc[mi][ni] = __builtin_amdgcn_mfma_f32_16x16x32_bf16(af[mi][0], bfr[ni][0], acc[mi][ni], 0, 0, 0);
            acc[mi][ni] = __builtin_amdgcn_mfma_f32_16x16x32_bf16(af[mi][1], bfr[ni][1], acc[mi][ni], 0, 0, 0);
        }
        __builtin_amdgcn_s_setprio(0);
        __syncthreads();
    }

    #pragma unroll
    for (int mi = 0; mi < 4; mi++)
    #pragma unroll
    for (int ni = 0; ni < 4; ni++)
    #pragma unroll
    for (int j = 0; j < 4; j++) {
        const int row = row0 + wr * 64 + mi * 16 + lhi * 4 + j;
        const int col = col0 + wc * 64 + ni * 16 + l15;
        float v = acc[mi][ni][j];
        if (EPI == 0) {
            C[(size_t)row * D_MODEL + col] = v;
        } else {
            if (col0 < D_MODEL) {                 // ---- Q, RoPE + prescale ----
                float pv = __shfl_xor(v, 1);
                int s  = row & (S_LEN - 1);
                int fi = (col & (HD - 1)) >> 1;
                float c  = fcos[s * (HD / 2) + fi];
                float sn = fsin[s * (HD / 2) + fi];
                float o = (col & 1) ? (pv * sn + v * c) : (v * c - pv * sn);
                Qb[(size_t)row * D_MODEL + col] = f2bf(o * QK_PRESCALE);
            } else if (col0 < D_MODEL + 256) {    // ---- K, RoPE ----
                int ck = col - D_MODEL;
                float pv = __shfl_xor(v, 1);
                int s  = row & (S_LEN - 1);
                int fi = (ck & (HD - 1)) >> 1;
                float c  = fcos[s * (HD / 2) + fi];
                float sn = fsin[s * (HD / 2) + fi];
                float o = (ck & 1) ? (pv * sn + v * c) : (v * c - pv * sn);
                Kb[(size_t)row * 256 + ck] = f2bf(o);
            } else {                              // ---- V, transposed store ----
                int cv = col - (D_MODEL + 256);
                int b = row >> 11, s = row & (S_LEN - 1);
                int kvh = cv >> 6, d = cv & (HD - 1);
                Vtb[((size_t)(b * HKV + kvh) * HD + d) * S_LEN + s] = f2bf(v);
            }
        }
    }
}

// ---------------- Flash attention v3: swapped QK^T + 2-way KV split ----------------
// Block = 128 threads (2 waves). Both waves own the same 32 q-rows; wave w does
// KV tiles t = w, w+2, ...; partial (m,l,O) merged via LDS at the end.
// Q pre-scaled by 0.125*log2e -> softmax in exp2 domain.
__global__ __launch_bounds__(128, 4) void flash_attn(
    const unsigned short* __restrict__ Q, const unsigned short* __restrict__ Kk,
    const unsigned short* __restrict__ Vt, unsigned short* __restrict__ O)
{
    const int tid  = threadIdx.x;
    const int lane = tid & 63;
    const int wid  = tid >> 6;           // wave 0/1
    const int l15 = lane & 15, lhi = lane >> 4;
    const int bid = blockIdx.x;
    const int h  = bid & 15;
    const int b  = (bid >> 4) & 1;
    const int qc = 63 - (bid >> 5);      // heavy chunks first
    const int kvh = h >> 2;
    const int qbase = qc * 32;

    __shared__ __align__(16) unsigned short plds[2][16][72];
    __shared__ __align__(16) float Olds[32][64];
    __shared__ float mlds[2][16], llds[2][16];

    short8 qf[2][2];
    #pragma unroll
    for (int qi = 0; qi < 2; qi++) {
        const unsigned short* qp =
            Q + ((size_t)(b * S_LEN + qbase + qi * 16 + l15) * HQ + h) * HD + lhi * 8;
        qf[qi][0] = *(const short8*)qp;
        qf[qi][1] = *(const short8*)(qp + 32);
    }

    floatx4 oacc[2][4] = {};
    float m_run[2] = {-1e30f, -1e30f};
    float l_run[2] = {0.f, 0.f};

    const unsigned short* kbase = Kk + ((size_t)(b * S_LEN) * HKV + kvh) * HD + lhi * 8;
    const unsigned short* vbase = Vt + (size_t)((b * HKV + kvh) * HD + l15) * S_LEN + lhi * 8;

    const int nt = (qbase + 31) / 64 + 1;     // KV tiles covering [0, qbase+31]

    for (int t = wid; t < nt; t += 2) {
        const int s0 = t * 64;
        short8 kf[4][2];
        #pragma unroll
        for (int st = 0; st < 4; st++) {
            const unsigned short* kp = kbase + (size_t)(s0 + st * 16 + l15) * (HKV * HD);
            kf[st][0] = *(const short8*)kp;
            kf[st][1] = *(const short8*)(kp + 32);
        }
        short8 vf[4][2];
        #pragma unroll
        for (int dct = 0; dct < 4; dct++) {
            const unsigned short* vp = vbase + (size_t)(dct * 16) * S_LEN + s0;
            vf[dct][0] = *(const short8*)vp;
            vf[dct][1] = *(const short8*)(vp + 32);
        }

        #pragma unroll
        for (int qi = 0; qi < 2; qi++) {
            const int qb = qbase + qi * 16;
            if (s0 > qb) continue;

            floatx4 sacc[4] = {};
            __builtin_amdgcn_s_setprio(1);
            #pragma unroll
            for (int st = 0; st < 4; st++) {
                sacc[st] = __builtin_amdgcn_mfma_f32_16x16x32_bf16(kf[st][0], qf[qi][0], sacc[st], 0, 0, 0);
                sacc[st] = __builtin_amdgcn_mfma_f32_16x16x32_bf16(kf[st][1], qf[qi][1], sacc[st], 0, 0, 0);
            }
            __builtin_amdgcn_s_setprio(0);

            const int q = qb + l15;
            if (s0 + 63 > qb) {              // diagonal tile: causal mask
                #pragma unroll
                for (int st = 0; st < 4; st++)
                #pragma unroll
                for (int j = 0; j < 4; j++) {
                    int s = s0 + st * 16 + lhi * 4 + j;
                    if (s > q) sacc[st][j] = -1e30f;
                }
            }

            float rmax = sacc[0][0];
            #pragma unroll
            for (int st = 0; st < 4; st++)
            #pragma unroll
            for (int j = 0; j < 4; j++) rmax = fmaxf(rmax, sacc[st][j]);
            rmax = fmaxf(rmax, __shfl_xor(rmax, 16));
            rmax = fmaxf(rmax, __shfl_xor(rmax, 32));

            // T13 defer-max (exp2 domain, P <= 2^8)
            if (!__all(rmax <= m_run[qi] + 8.0f)) {
                float mnew = fmaxf(m_run[qi], rmax);
                float rr = exp2_hw(m_run[qi] - mnew);
                m_run[qi] = mnew;
                l_run[qi] *= rr;
                #pragma unroll
                for (int dct = 0; dct < 4; dct++)
                #pragma unroll
                for (int j = 0; j < 4; j++) oacc[qi][dct][j] *= rr;
            }
            const float mcur = m_run[qi];

            float psum = 0.f;
            unsigned int pk[4][2];
            #pragma unroll
            for (int st = 0; st < 4; st++) {
                float p0 = exp2_hw(sacc[st][0] - mcur);
                float p1 = exp2_hw(sacc[st][1] - mcur);
                float p2 = exp2_hw(sacc[st][2] - mcur);
                float p3 = exp2_hw(sacc[st][3] - mcur);
                psum += (p0 + p1) + (p2 + p3);
                pk[st][0] = cvt_pk_bf16(p0, p1);
                pk[st][1] = cvt_pk_bf16(p2, p3);
            }
            psum += __shfl_xor(psum, 16);
            psum += __shfl_xor(psum, 32);
            l_run[qi] += psum;

            #pragma unroll
            for (int st = 0; st < 4; st++) {
                *(unsigned int*)&plds[wid][l15][st * 16 + lhi * 4 + 0] = pk[st][0];
                *(unsigned int*)&plds[wid][l15][st * 16 + lhi * 4 + 2] = pk[st][1];
            }
            short8 pf0 = *(const short8*)&plds[wid][l15][lhi * 8];
            short8 pf1 = *(const short8*)&plds[wid][l15][32 + lhi * 8];

            __builtin_amdgcn_s_setprio(1);
            #pragma unroll
            for (int dct = 0; dct < 4; dct++) {
                oacc[qi][dct] = __builtin_amdgcn_mfma_f32_16x16x32_bf16(vf[dct][0], pf0, oacc[qi][dct], 0, 0, 0);
                oacc[qi][dct] = __builtin_amdgcn_mfma_f32_16x16x32_bf16(vf[dct][1], pf1, oacc[qi][dct], 0, 0, 0);
            }
            __builtin_amdgcn_s_setprio(0);
        }
    }

    // ---- cross-wave combine ----
    if (wid == 1) {
        #pragma unroll
        for (int qi = 0; qi < 2; qi++) {
            if (lhi == 0) { mlds[qi][l15] = m_run[qi]; llds[qi][l15] = l_run[qi]; }
            #pragma unroll
            for (int dct = 0; dct < 4; dct++)
            #pragma unroll
            for (int j = 0; j < 4; j++)
                Olds[qi * 16 + dct * 4 + j][lane] = oacc[qi][dct][j];
        }
    }
    __syncthreads();
    if (wid == 0) {
        #pragma unroll
        for (int qi = 0; qi < 2; qi++) {
            float m1 = mlds[qi][l15], l1 = llds[qi][l15];
            float m  = fmaxf(m_run[qi], m1);
            float f0 = exp2_hw(m_run[qi] - m);
            float f1 = exp2_hw(m1 - m);
            float rl = 1.0f / (l_run[qi] * f0 + l1 * f1);
            float s0f = f0 * rl, s1f = f1 * rl;
            const int q = qbase + qi * 16 + l15;
            unsigned short* op = O + ((size_t)(b * S_LEN + q) * HQ + h) * HD + lhi * 4;
            #pragma unroll
            for (int dct = 0; dct < 4; dct++) {
                float o0 = oacc[qi][dct][0] * s0f + Olds[qi * 16 + dct * 4 + 0][lane] * s1f;
                float o1 = oacc[qi][dct][1] * s0f + Olds[qi * 16 + dct * 4 + 1][lane] * s1f;
                float o2 = oacc[qi][dct][2] * s0f + Olds[qi * 16 + dct * 4 + 2][lane] * s1f;
                float o3 = oacc[qi][dct][3] * s0f + Olds[qi * 16 + dct * 4 + 3][lane] * s1f;
                *(unsigned int*)(op + dct * 16)     = cvt_pk_bf16(o0, o1);
                *(unsigned int*)(op + dct * 16 + 2) = cvt_pk_bf16(o2, o3);
            }
        }
    }
}

extern "C" void kernel_launch(void* const* d_in, const int* in_sizes, int n_in,
                              void* d_out, int out_size, void* d_ws, size_t ws_size,
                              hipStream_t stream) {
    const float* x    = (const float*)d_in[0];
    const float* wq   = (const float*)d_in[1];
    const float* wk   = (const float*)d_in[2];
    const float* wv   = (const float*)d_in[3];
    const float* wo   = (const float*)d_in[4];
    const float* fcos = (const float*)d_in[5];
    const float* fsin = (const float*)d_in[6];
    float* out = (float*)d_out;

    char* ws = (char*)d_ws;
    unsigned short* xb    = (unsigned short*)(ws);              // 8 MB
    unsigned short* wqkvb = (unsigned short*)(ws + 8388608);    // 3 MB [1536][1024]
    unsigned short* wob   = (unsigned short*)(ws + 11534336);   // 2 MB (contiguous after wqkvb)
    unsigned short* Qb    = (unsigned short*)(ws + 13631488);   // 8 MB
    unsigned short* Kb    = (unsigned short*)(ws + 22020096);   // 2 MB
    unsigned short* Vtb   = (unsigned short*)(ws + 24117248);   // 2 MB
    unsigned short* Ab    = (unsigned short*)(ws + 26214400);   // 8 MB

    cvt_f32_bf16<<<1024, 256, 0, stream>>>(x, xb, 4096 * 1024);
    cvt_weights<<<2560, 256, 0, stream>>>(wq, wk, wv, wo, wqkvb);

    gemm128<1><<<dim3(32, 12), 256, 0, stream>>>(xb, wqkvb, nullptr, Qb, Kb, Vtb,
                                                 fcos, fsin, 1024, 1536);

    flash_attn<<<64 * 32, 128, 0, stream>>>(Qb, Kb, Vtb, Ab);

    gemm128<0><<<dim3(32, 8), 256, 0, stream>>>(Ab, wob, out, nullptr, nullptr, nullptr,
                                                nullptr, nullptr, 1024, 1024);
}

// Round 5
// 139.849 us; speedup vs baseline: 1.5735x; 1.5735x over previous
//
#include <hip/hip_runtime.h>
#include <hip/hip_bf16.h>

typedef __attribute__((ext_vector_type(8))) short short8;
typedef __attribute__((ext_vector_type(4))) float floatx4;
typedef __attribute__((ext_vector_type(4))) float float4v;
typedef __attribute__((ext_vector_type(4))) unsigned short ushort4v;

#define S_LEN 2048
#define D_MODEL 1024
#define HD 64
#define HQ 16
#define HKV 4
#define QK_PRESCALE 0.18033688011112042f   // 0.125 * log2(e) -> softmax in exp2 domain

__device__ __forceinline__ unsigned short f2bf(float f) {
    unsigned int u = __builtin_bit_cast(unsigned int, f);
    u += 0x7fffu + ((u >> 16) & 1u);   // RNE
    return (unsigned short)(u >> 16);
}

__device__ __forceinline__ unsigned int cvt_pk_bf16(float lo, float hi) {
    unsigned int r;
    asm volatile("v_cvt_pk_bf16_f32 %0, %1, %2" : "=v"(r) : "v"(lo), "v"(hi));
    return r;
}

__device__ __forceinline__ float exp2_hw(float x) {
    float r;
    asm("v_exp_f32 %0, %1" : "=v"(r) : "v"(x));
    return r;
}

__device__ __forceinline__ void gload16(const unsigned short* g, unsigned short* l) {
    __builtin_amdgcn_global_load_lds(
        (const __attribute__((address_space(1))) void*)g,
        (__attribute__((address_space(3))) void*)l, 16, 0, 0);
}

// ---------------- f32 -> bf16 converts ----------------
__global__ void cvt_f32_bf16(const float* __restrict__ in, unsigned short* __restrict__ out, int n) {
    int i = (blockIdx.x * blockDim.x + threadIdx.x) * 4;
    int stride = gridDim.x * blockDim.x * 4;
    for (; i < n; i += stride) {
        float4v v = *(const float4v*)(in + i);
        ushort4v o;
        o.x = f2bf(v.x); o.y = f2bf(v.y); o.z = f2bf(v.z); o.w = f2bf(v.w);
        *(ushort4v*)(out + i) = o;
    }
}

// dst: [wq 1M][wk 256k][wv 256k][wo 1M] contiguous bf16 (2.5M elems)
__global__ void cvt_weights(const float* __restrict__ wq, const float* __restrict__ wk,
                            const float* __restrict__ wv, const float* __restrict__ wo,
                            unsigned short* __restrict__ dst) {
    int i = (blockIdx.x * blockDim.x + threadIdx.x) * 4;
    const float* src; int off;
    if (i < 1048576)      { src = wq; off = i; }
    else if (i < 1310720) { src = wk; off = i - 1048576; }
    else if (i < 1572864) { src = wv; off = i - 1310720; }
    else                  { src = wo; off = i - 1572864; }
    float4v v = *(const float4v*)(src + off);
    ushort4v o;
    o.x = f2bf(v.x); o.y = f2bf(v.y); o.z = f2bf(v.z); o.w = f2bf(v.w);
    *(ushort4v*)(dst + i) = o;
}

// ---------------- GEMM 128x128, BK=64, global_load_lds + XOR swizzle ----------
template<int EPI>
__global__ __launch_bounds__(256) void gemm128(
    const unsigned short* __restrict__ A, const unsigned short* __restrict__ W,
    float* __restrict__ C,
    unsigned short* __restrict__ Qb, unsigned short* __restrict__ Kb, unsigned short* __restrict__ Vtb,
    const float* __restrict__ fcos, const float* __restrict__ fsin,
    int K, int N)
{
    __shared__ __align__(16) unsigned short Asm[128 * 64];
    __shared__ __align__(16) unsigned short Bsm[128 * 64];

    const int tid  = threadIdx.x;
    const int lane = tid & 63;
    const int w    = tid >> 6;
    const int wr   = w >> 1, wc = w & 1;
    const int l15  = lane & 15, lhi = lane >> 4;
    const int row0 = blockIdx.x * 128;
    const int col0 = blockIdx.y * 128;

    const int r_in = tid >> 3;           // 0..31
    const int sp   = tid & 7;
    const int sl   = sp ^ (r_in & 7);    // inverse-swizzled source slot

    floatx4 acc[4][4] = {};

    for (int k0 = 0; k0 < K; k0 += 64) {
        #pragma unroll
        for (int i = 0; i < 4; i++) {
            const int r = i * 32 + r_in;
            gload16(A + (size_t)(row0 + r) * K + k0 + sl * 8, Asm + i * 2048 + w * 512);
            gload16(W + (size_t)(col0 + r) * K + k0 + sl * 8, Bsm + i * 2048 + w * 512);
        }
        __syncthreads();

        short8 af[4][2], bfr[4][2];
        const int rx = l15 & 7;
        #pragma unroll
        for (int mi = 0; mi < 4; mi++) {
            const int rowa = wr * 64 + mi * 16 + l15;
            const int rowb = wc * 64 + mi * 16 + l15;
            #pragma unroll
            for (int ks = 0; ks < 2; ks++) {
                const int slot = (ks * 4 + lhi) ^ rx;
                af[mi][ks]  = *(const short8*)&Asm[rowa * 64 + slot * 8];
                bfr[mi][ks] = *(const short8*)&Bsm[rowb * 64 + slot * 8];
            }
        }

        __builtin_amdgcn_s_setprio(1);
        #pragma unroll
        for (int mi = 0; mi < 4; mi++)
        #pragma unroll
        for (int ni = 0; ni < 4; ni++) {
            acc[mi][ni] = __builtin_amdgcn_mfma_f32_16x16x32_bf16(af[mi][0], bfr[ni][0], acc[mi][ni], 0, 0, 0);
            acc[mi][ni] = __builtin_amdgcn_mfma_f32_16x16x32_bf16(af[mi][1], bfr[ni][1], acc[mi][ni], 0, 0, 0);
        }
        __builtin_amdgcn_s_setprio(0);
        __syncthreads();
    }

    #pragma unroll
    for (int mi = 0; mi < 4; mi++)
    #pragma unroll
    for (int ni = 0; ni < 4; ni++)
    #pragma unroll
    for (int j = 0; j < 4; j++) {
        const int row = row0 + wr * 64 + mi * 16 + lhi * 4 + j;
        const int col = col0 + wc * 64 + ni * 16 + l15;
        float v = acc[mi][ni][j];
        if (EPI == 0) {
            C[(size_t)row * D_MODEL + col] = v;
        } else {
            if (col0 < D_MODEL) {                 // ---- Q, RoPE + prescale ----
                float pv = __shfl_xor(v, 1);
                int s  = row & (S_LEN - 1);
                int fi = (col & (HD - 1)) >> 1;
                float c  = fcos[s * (HD / 2) + fi];
                float sn = fsin[s * (HD / 2) + fi];
                float o = (col & 1) ? (pv * sn + v * c) : (v * c - pv * sn);
                Qb[(size_t)row * D_MODEL + col] = f2bf(o * QK_PRESCALE);
            } else if (col0 < D_MODEL + 256) {    // ---- K, RoPE ----
                int ck = col - D_MODEL;
                float pv = __shfl_xor(v, 1);
                int s  = row & (S_LEN - 1);
                int fi = (ck & (HD - 1)) >> 1;
                float c  = fcos[s * (HD / 2) + fi];
                float sn = fsin[s * (HD / 2) + fi];
                float o = (ck & 1) ? (pv * sn + v * c) : (v * c - pv * sn);
                Kb[(size_t)row * 256 + ck] = f2bf(o);
            } else {                              // ---- V, transposed store ----
                int cv = col - (D_MODEL + 256);
                int b = row >> 11, s = row & (S_LEN - 1);
                int kvh = cv >> 6, d = cv & (HD - 1);
                Vtb[((size_t)(b * HKV + kvh) * HD + d) * S_LEN + s] = f2bf(v);
            }
        }
    }
}

// ---------------- Flash attention v4: swapped QK^T, 4-way KV split, K/V reg time-share --
// Block = 256 threads (4 waves), all owning the same 32 q-rows. Wave w does KV
// tiles t = w, w+4, ...; partial (m,l,O) merged via LDS at the end.
// Q pre-scaled by 0.125*log2e -> softmax in exp2 domain.
__global__ __launch_bounds__(256) void flash_attn(
    const unsigned short* __restrict__ Q, const unsigned short* __restrict__ Kk,
    const unsigned short* __restrict__ Vt, unsigned short* __restrict__ O)
{
    const int tid  = threadIdx.x;
    const int lane = tid & 63;
    const int wid  = tid >> 6;           // wave 0..3
    const int l15 = lane & 15, lhi = lane >> 4;
    const int bid = blockIdx.x;
    const int h  = bid & 15;
    const int b  = (bid >> 4) & 1;
    const int qc = 63 - (bid >> 5);      // heavy chunks first
    const int kvh = h >> 2;
    const int qbase = qc * 32;

    __shared__ __align__(16) unsigned short plds[4][16][72];
    __shared__ __align__(16) float Olds[3][32][64];
    __shared__ float mlds[3][2][16], llds[3][2][16];

    short8 qf[2][2];
    #pragma unroll
    for (int qi = 0; qi < 2; qi++) {
        const unsigned short* qp =
            Q + ((size_t)(b * S_LEN + qbase + qi * 16 + l15) * HQ + h) * HD + lhi * 8;
        qf[qi][0] = *(const short8*)qp;
        qf[qi][1] = *(const short8*)(qp + 32);
    }

    floatx4 oacc[2][4] = {};
    float m_run[2] = {-1e30f, -1e30f};
    float l_run[2] = {0.f, 0.f};

    const unsigned short* kbase = Kk + ((size_t)(b * S_LEN) * HKV + kvh) * HD + lhi * 8;
    const unsigned short* vbase = Vt + (size_t)((b * HKV + kvh) * HD + l15) * S_LEN + lhi * 8;

    const int nt = (qbase + 31) / 64 + 1;     // KV tiles covering [0, qbase+31]

    for (int t = wid; t < nt; t += 4) {
        const int s0 = t * 64;

        // ---- K fragments into time-shared kv regs ----
        short8 kv[4][2];
        #pragma unroll
        for (int st = 0; st < 4; st++) {
            const unsigned short* kp = kbase + (size_t)(s0 + st * 16 + l15) * (HKV * HD);
            kv[st][0] = *(const short8*)kp;
            kv[st][1] = *(const short8*)(kp + 32);
        }

        // ---- QK^T for both q-subtiles (s0 <= qbase always; both active) ----
        floatx4 sacc[2][4] = {};
        __builtin_amdgcn_s_setprio(1);
        #pragma unroll
        for (int qi = 0; qi < 2; qi++)
        #pragma unroll
        for (int st = 0; st < 4; st++) {
            sacc[qi][st] = __builtin_amdgcn_mfma_f32_16x16x32_bf16(kv[st][0], qf[qi][0], sacc[qi][st], 0, 0, 0);
            sacc[qi][st] = __builtin_amdgcn_mfma_f32_16x16x32_bf16(kv[st][1], qf[qi][1], sacc[qi][st], 0, 0, 0);
        }
        __builtin_amdgcn_s_setprio(0);

        // ---- V fragments overwrite kv (WAR: issue after MFMAs; latency hides under softmax) --
        #pragma unroll
        for (int dct = 0; dct < 4; dct++) {
            const unsigned short* vp = vbase + (size_t)(dct * 16) * S_LEN + s0;
            kv[dct][0] = *(const short8*)vp;
            kv[dct][1] = *(const short8*)(vp + 32);
        }

        // ---- softmax per q-subtile ----
        short8 pf[2][2];
        #pragma unroll
        for (int qi = 0; qi < 2; qi++) {
            const int qb = qbase + qi * 16;
            const int q = qb + l15;
            if (s0 + 63 > qb) {              // diagonal tile: causal mask
                #pragma unroll
                for (int st = 0; st < 4; st++)
                #pragma unroll
                for (int j = 0; j < 4; j++) {
                    int s = s0 + st * 16 + lhi * 4 + j;
                    if (s > q) sacc[qi][st][j] = -1e30f;
                }
            }

            float rmax = sacc[qi][0][0];
            #pragma unroll
            for (int st = 0; st < 4; st++)
            #pragma unroll
            for (int j = 0; j < 4; j++) rmax = fmaxf(rmax, sacc[qi][st][j]);
            rmax = fmaxf(rmax, __shfl_xor(rmax, 16));
            rmax = fmaxf(rmax, __shfl_xor(rmax, 32));

            // T13 defer-max (exp2 domain, P <= 2^8)
            if (!__all(rmax <= m_run[qi] + 8.0f)) {
                float mnew = fmaxf(m_run[qi], rmax);
                float rr = exp2_hw(m_run[qi] - mnew);
                m_run[qi] = mnew;
                l_run[qi] *= rr;
                #pragma unroll
                for (int dct = 0; dct < 4; dct++)
                #pragma unroll
                for (int j = 0; j < 4; j++) oacc[qi][dct][j] *= rr;
            }
            const float mcur = m_run[qi];

            float psum = 0.f;
            unsigned int pk[4][2];
            #pragma unroll
            for (int st = 0; st < 4; st++) {
                float p0 = exp2_hw(sacc[qi][st][0] - mcur);
                float p1 = exp2_hw(sacc[qi][st][1] - mcur);
                float p2 = exp2_hw(sacc[qi][st][2] - mcur);
                float p3 = exp2_hw(sacc[qi][st][3] - mcur);
                psum += (p0 + p1) + (p2 + p3);
                pk[st][0] = cvt_pk_bf16(p0, p1);
                pk[st][1] = cvt_pk_bf16(p2, p3);
            }
            psum += __shfl_xor(psum, 16);
            psum += __shfl_xor(psum, 32);
            l_run[qi] += psum;

            #pragma unroll
            for (int st = 0; st < 4; st++) {
                *(unsigned int*)&plds[wid][l15][st * 16 + lhi * 4 + 0] = pk[st][0];
                *(unsigned int*)&plds[wid][l15][st * 16 + lhi * 4 + 2] = pk[st][1];
            }
            pf[qi][0] = *(const short8*)&plds[wid][l15][lhi * 8];
            pf[qi][1] = *(const short8*)&plds[wid][l15][32 + lhi * 8];
        }

        // ---- PV for both q-subtiles (kv now holds V) ----
        __builtin_amdgcn_s_setprio(1);
        #pragma unroll
        for (int qi = 0; qi < 2; qi++)
        #pragma unroll
        for (int dct = 0; dct < 4; dct++) {
            oacc[qi][dct] = __builtin_amdgcn_mfma_f32_16x16x32_bf16(kv[dct][0], pf[qi][0], oacc[qi][dct], 0, 0, 0);
            oacc[qi][dct] = __builtin_amdgcn_mfma_f32_16x16x32_bf16(kv[dct][1], pf[qi][1], oacc[qi][dct], 0, 0, 0);
        }
        __builtin_amdgcn_s_setprio(0);
    }

    // ---- cross-wave combine (waves 1..3 -> LDS, wave 0 merges) ----
    if (wid >= 1) {
        #pragma unroll
        for (int qi = 0; qi < 2; qi++) {
            if (lhi == 0) { mlds[wid - 1][qi][l15] = m_run[qi]; llds[wid - 1][qi][l15] = l_run[qi]; }
            #pragma unroll
            for (int dct = 0; dct < 4; dct++)
            #pragma unroll
            for (int j = 0; j < 4; j++)
                Olds[wid - 1][qi * 16 + dct * 4 + j][lane] = oacc[qi][dct][j];
        }
    }
    __syncthreads();
    if (wid == 0) {
        #pragma unroll
        for (int qi = 0; qi < 2; qi++) {
            float mw0 = mlds[0][qi][l15], lw0 = llds[0][qi][l15];
            float mw1 = mlds[1][qi][l15], lw1 = llds[1][qi][l15];
            float mw2 = mlds[2][qi][l15], lw2 = llds[2][qi][l15];
            float mm = fmaxf(fmaxf(m_run[qi], mw0), fmaxf(mw1, mw2));
            float fs = exp2_hw(m_run[qi] - mm);
            float f0 = exp2_hw(mw0 - mm);
            float f1 = exp2_hw(mw1 - mm);
            float f2 = exp2_hw(mw2 - mm);
            float rl = 1.0f / (l_run[qi] * fs + lw0 * f0 + lw1 * f1 + lw2 * f2);
            fs *= rl; f0 *= rl; f1 *= rl; f2 *= rl;
            const int q = qbase + qi * 16 + l15;
            unsigned short* op = O + ((size_t)(b * S_LEN + q) * HQ + h) * HD + lhi * 4;
            #pragma unroll
            for (int dct = 0; dct < 4; dct++) {
                float o[4];
                #pragma unroll
                for (int j = 0; j < 4; j++) {
                    const int r = qi * 16 + dct * 4 + j;
                    o[j] = oacc[qi][dct][j] * fs + Olds[0][r][lane] * f0
                         + Olds[1][r][lane] * f1 + Olds[2][r][lane] * f2;
                }
                *(unsigned int*)(op + dct * 16)     = cvt_pk_bf16(o[0], o[1]);
                *(unsigned int*)(op + dct * 16 + 2) = cvt_pk_bf16(o[2], o[3]);
            }
        }
    }
}

extern "C" void kernel_launch(void* const* d_in, const int* in_sizes, int n_in,
                              void* d_out, int out_size, void* d_ws, size_t ws_size,
                              hipStream_t stream) {
    const float* x    = (const float*)d_in[0];
    const float* wq   = (const float*)d_in[1];
    const float* wk   = (const float*)d_in[2];
    const float* wv   = (const float*)d_in[3];
    const float* wo   = (const float*)d_in[4];
    const float* fcos = (const float*)d_in[5];
    const float* fsin = (const float*)d_in[6];
    float* out = (float*)d_out;

    char* ws = (char*)d_ws;
    unsigned short* xb    = (unsigned short*)(ws);              // 8 MB
    unsigned short* wqkvb = (unsigned short*)(ws + 8388608);    // 3 MB [1536][1024]
    unsigned short* wob   = (unsigned short*)(ws + 11534336);   // 2 MB
    unsigned short* Qb    = (unsigned short*)(ws + 13631488);   // 8 MB
    unsigned short* Kb    = (unsigned short*)(ws + 22020096);   // 2 MB
    unsigned short* Vtb   = (unsigned short*)(ws + 24117248);   // 2 MB
    unsigned short* Ab    = (unsigned short*)(ws + 26214400);   // 8 MB

    cvt_f32_bf16<<<1024, 256, 0, stream>>>(x, xb, 4096 * 1024);
    cvt_weights<<<2560, 256, 0, stream>>>(wq, wk, wv, wo, wqkvb);

    gemm128<1><<<dim3(32, 12), 256, 0, stream>>>(xb, wqkvb, nullptr, Qb, Kb, Vtb,
                                                 fcos, fsin, 1024, 1536);

    flash_attn<<<64 * 32, 256, 0, stream>>>(Qb, Kb, Vtb, Ab);

    gemm128<0><<<dim3(32, 8), 256, 0, stream>>>(Ab, wob, out, nullptr, nullptr, nullptr,
                                                nullptr, nullptr, 1024, 1024);
}

// Round 6
// 126.481 us; speedup vs baseline: 1.7398x; 1.1057x over previous
//
#include <hip/hip_runtime.h>
#include <hip/hip_bf16.h>

typedef __attribute__((ext_vector_type(8))) short short8;
typedef __attribute__((ext_vector_type(4))) float floatx4;
typedef __attribute__((ext_vector_type(4))) float float4v;
typedef __attribute__((ext_vector_type(4))) unsigned short ushort4v;

#define S_LEN 2048
#define D_MODEL 1024
#define HD 64
#define HQ 16
#define HKV 4
#define QK_PRESCALE 0.18033688011112042f   // 0.125 * log2(e) -> softmax in exp2 domain

__device__ __forceinline__ unsigned short f2bf(float f) {
    unsigned int u = __builtin_bit_cast(unsigned int, f);
    u += 0x7fffu + ((u >> 16) & 1u);   // RNE
    return (unsigned short)(u >> 16);
}

__device__ __forceinline__ unsigned int cvt_pk_bf16(float lo, float hi) {
    unsigned int r;
    asm volatile("v_cvt_pk_bf16_f32 %0, %1, %2" : "=v"(r) : "v"(lo), "v"(hi));
    return r;
}

__device__ __forceinline__ float exp2_hw(float x) {
    float r;
    asm("v_exp_f32 %0, %1" : "=v"(r) : "v"(x));
    return r;
}

__device__ __forceinline__ void gload16(const unsigned short* g, unsigned short* l) {
    __builtin_amdgcn_global_load_lds(
        (const __attribute__((address_space(1))) void*)g,
        (__attribute__((address_space(3))) void*)l, 16, 0, 0);
}

// ---------------- f32 -> bf16 converts ----------------
__global__ void cvt_f32_bf16(const float* __restrict__ in, unsigned short* __restrict__ out, int n) {
    int i = (blockIdx.x * blockDim.x + threadIdx.x) * 4;
    int stride = gridDim.x * blockDim.x * 4;
    for (; i < n; i += stride) {
        float4v v = *(const float4v*)(in + i);
        ushort4v o;
        o.x = f2bf(v.x); o.y = f2bf(v.y); o.z = f2bf(v.z); o.w = f2bf(v.w);
        *(ushort4v*)(out + i) = o;
    }
}

// dst: [wq 1M][wk 256k][wv 256k][wo 1M] contiguous bf16 (2.5M elems)
__global__ void cvt_weights(const float* __restrict__ wq, const float* __restrict__ wk,
                            const float* __restrict__ wv, const float* __restrict__ wo,
                            unsigned short* __restrict__ dst) {
    int i = (blockIdx.x * blockDim.x + threadIdx.x) * 4;
    const float* src; int off;
    if (i < 1048576)      { src = wq; off = i; }
    else if (i < 1310720) { src = wk; off = i - 1048576; }
    else if (i < 1572864) { src = wv; off = i - 1310720; }
    else                  { src = wo; off = i - 1572864; }
    float4v v = *(const float4v*)(src + off);
    ushort4v o;
    o.x = f2bf(v.x); o.y = f2bf(v.y); o.z = f2bf(v.z); o.w = f2bf(v.w);
    *(ushort4v*)(dst + i) = o;
}

// ---------------- GEMM 128x128, BK=64, global_load_lds + XOR swizzle ----------
template<int EPI>
__global__ __launch_bounds__(256) void gemm128(
    const unsigned short* __restrict__ A, const unsigned short* __restrict__ W,
    float* __restrict__ C,
    unsigned short* __restrict__ Qb, unsigned short* __restrict__ Kb, unsigned short* __restrict__ Vtb,
    const float* __restrict__ fcos, const float* __restrict__ fsin,
    int K, int N)
{
    __shared__ __align__(16) unsigned short Asm[128 * 64];
    __shared__ __align__(16) unsigned short Bsm[128 * 64];

    const int tid  = threadIdx.x;
    const int lane = tid & 63;
    const int w    = tid >> 6;
    const int wr   = w >> 1, wc = w & 1;
    const int l15  = lane & 15, lhi = lane >> 4;
    const int row0 = blockIdx.x * 128;
    const int col0 = blockIdx.y * 128;

    const int r_in = tid >> 3;           // 0..31
    const int sp   = tid & 7;
    const int sl   = sp ^ (r_in & 7);    // inverse-swizzled source slot

    floatx4 acc[4][4] = {};

    for (int k0 = 0; k0 < K; k0 += 64) {
        #pragma unroll
        for (int i = 0; i < 4; i++) {
            const int r = i * 32 + r_in;
            gload16(A + (size_t)(row0 + r) * K + k0 + sl * 8, Asm + i * 2048 + w * 512);
            gload16(W + (size_t)(col0 + r) * K + k0 + sl * 8, Bsm + i * 2048 + w * 512);
        }
        __syncthreads();

        short8 af[4][2], bfr[4][2];
        const int rx = l15 & 7;
        #pragma unroll
        for (int mi = 0; mi < 4; mi++) {
            const int rowa = wr * 64 + mi * 16 + l15;
            const int rowb = wc * 64 + mi * 16 + l15;
            #pragma unroll
            for (int ks = 0; ks < 2; ks++) {
                const int slot = (ks * 4 + lhi) ^ rx;
                af[mi][ks]  = *(const short8*)&Asm[rowa * 64 + slot * 8];
                bfr[mi][ks] = *(const short8*)&Bsm[rowb * 64 + slot * 8];
            }
        }

        __builtin_amdgcn_s_setprio(1);
        #pragma unroll
        for (int mi = 0; mi < 4; mi++)
        #pragma unroll
        for (int ni = 0; ni < 4; ni++) {
            acc[mi][ni] = __builtin_amdgcn_mfma_f32_16x16x32_bf16(af[mi][0], bfr[ni][0], acc[mi][ni], 0, 0, 0);
            acc[mi][ni] = __builtin_amdgcn_mfma_f32_16x16x32_bf16(af[mi][1], bfr[ni][1], acc[mi][ni], 0, 0, 0);
        }
        __builtin_amdgcn_s_setprio(0);
        __syncthreads();
    }

    #pragma unroll
    for (int mi = 0; mi < 4; mi++)
    #pragma unroll
    for (int ni = 0; ni < 4; ni++)
    #pragma unroll
    for (int j = 0; j < 4; j++) {
        const int row = row0 + wr * 64 + mi * 16 + lhi * 4 + j;
        const int col = col0 + wc * 64 + ni * 16 + l15;
        float v = acc[mi][ni][j];
        if (EPI == 0) {
            C[(size_t)row * D_MODEL + col] = v;
        } else {
            if (col0 < D_MODEL) {                 // ---- Q, RoPE + prescale ----
                float pv = __shfl_xor(v, 1);
                int s  = row & (S_LEN - 1);
                int fi = (col & (HD - 1)) >> 1;
                float c  = fcos[s * (HD / 2) + fi];
                float sn = fsin[s * (HD / 2) + fi];
                float o = (col & 1) ? (pv * sn + v * c) : (v * c - pv * sn);
                Qb[(size_t)row * D_MODEL + col] = f2bf(o * QK_PRESCALE);
            } else if (col0 < D_MODEL + 256) {    // ---- K, RoPE ----
                int ck = col - D_MODEL;
                float pv = __shfl_xor(v, 1);
                int s  = row & (S_LEN - 1);
                int fi = (ck & (HD - 1)) >> 1;
                float c  = fcos[s * (HD / 2) + fi];
                float sn = fsin[s * (HD / 2) + fi];
                float o = (ck & 1) ? (pv * sn + v * c) : (v * c - pv * sn);
                Kb[(size_t)row * 256 + ck] = f2bf(o);
            } else {                              // ---- V, transposed store ----
                int cv = col - (D_MODEL + 256);
                int b = row >> 11, s = row & (S_LEN - 1);
                int kvh = cv >> 6, d = cv & (HD - 1);
                Vtb[((size_t)(b * HKV + kvh) * HD + d) * S_LEN + s] = f2bf(v);
            }
        }
    }
}

// ---------------- Flash attention v5: shared-KV LDS staging + 2-phase prefetch ------
// Block = (b, kvh, q-chunk of 32 rows): 4 waves = the 4 q-heads sharing kvh.
// Per KV tile (64): stage K(64x64) + Vt(64x64) into LDS once (global_load_lds,
// inverse-XOR-swizzled source), all 4 waves read fragments from LDS.
// Swapped QK^T (S[s][q]); softmax in exp2 domain; per-wave O epilogue (no merge).
__global__ __launch_bounds__(256) void flash_attn(
    const unsigned short* __restrict__ Q, const unsigned short* __restrict__ Kk,
    const unsigned short* __restrict__ Vt, unsigned short* __restrict__ O)
{
    const int tid  = threadIdx.x;
    const int lane = tid & 63;
    const int wid  = tid >> 6;           // q-head within kv group
    const int l15 = lane & 15, lhi = lane >> 4;
    const int bid = blockIdx.x;
    const int g   = bid & 7;
    const int b   = g >> 2, kvh = g & 3;
    const int i   = bid >> 3;            // 0..63
    const int qc  = (i < 32) ? (63 - i) : (i - 32);   // complement pairing (i, i+32)
    const int h   = kvh * 4 + wid;
    const int qbase = qc * 32;

    __shared__ __align__(16) unsigned short Klds[2][64 * 64];
    __shared__ __align__(16) unsigned short Vlds[2][64 * 64];
    __shared__ __align__(16) unsigned short plds[4][16][72];

    // ---- Q fragments (B-frag: lane l15 = q col, k = d) ----
    short8 qf[2][2];
    #pragma unroll
    for (int qi = 0; qi < 2; qi++) {
        const unsigned short* qp =
            Q + ((size_t)(b * S_LEN + qbase + qi * 16 + l15) * HQ + h) * HD + lhi * 8;
        qf[qi][0] = *(const short8*)qp;
        qf[qi][1] = *(const short8*)(qp + 32);
    }

    floatx4 oacc[2][4] = {};
    float m_run[2] = {-1e30f, -1e30f};
    float l_run[2] = {0.f, 0.f};

    // staging thread decomposition: unit u = j*256+tid -> row r = u>>3, slot = u&7
    const int r_st  = tid >> 3;            // row within 32-row group
    const int sl_st = tid & 7;
    const unsigned short* ksrc = Kk + (size_t)(b * S_LEN) * 256 + kvh * 64;
    const unsigned short* vsrc = Vt + (size_t)((b * HKV + kvh) * HD) * S_LEN;
    const int ldsbase = (wid * 64) * 8;    // uniform per wave; lane adds 16B

    const int nt = (qbase + 31) / 64 + 1;  // KV tiles covering [0, qbase+31]

    // prologue: stage tile 0 into buf 0
    {
        const int s0 = 0;
        #pragma unroll
        for (int j = 0; j < 2; j++) {
            const int r  = j * 32 + r_st;
            const int sl = sl_st ^ (r & 7);
            gload16(ksrc + (size_t)(s0 + r) * 256 + sl * 8,   &Klds[0][j * 2048 + ldsbase]);
            gload16(vsrc + (size_t)r * S_LEN + s0 + sl * 8,   &Vlds[0][j * 2048 + ldsbase]);
        }
    }
    asm volatile("s_waitcnt vmcnt(0)" ::: "memory");
    __syncthreads();

    const int rsw = l15 & 7;               // fragment-read swizzle key

    for (int t = 0; t < nt; t++) {
        const int s0  = t * 64;
        const int buf = t & 1;

        // ---- issue next tile's staging early (hides under compute) ----
        if (t + 1 < nt) {
            const int s1 = s0 + 64;
            #pragma unroll
            for (int j = 0; j < 2; j++) {
                const int r  = j * 32 + r_st;
                const int sl = sl_st ^ (r & 7);
                gload16(ksrc + (size_t)(s1 + r) * 256 + sl * 8, &Klds[buf ^ 1][j * 2048 + ldsbase]);
                gload16(vsrc + (size_t)r * S_LEN + s1 + sl * 8, &Vlds[buf ^ 1][j * 2048 + ldsbase]);
            }
        }

        // ---- K fragments from LDS (A-frag: lane l15 = s row, k = d) ----
        short8 kf[4][2];
        #pragma unroll
        for (int st = 0; st < 4; st++) {
            const int row = st * 16 + l15;
            #pragma unroll
            for (int half = 0; half < 2; half++) {
                const int slot = ((half << 2) | lhi) ^ rsw;
                kf[st][half] = *(const short8*)&Klds[buf][row * 64 + slot * 8];
            }
        }

        // ---- QK^T for both q-subtiles ----
        floatx4 sacc[2][4] = {};
        __builtin_amdgcn_s_setprio(1);
        #pragma unroll
        for (int qi = 0; qi < 2; qi++)
        #pragma unroll
        for (int st = 0; st < 4; st++) {
            sacc[qi][st] = __builtin_amdgcn_mfma_f32_16x16x32_bf16(kf[st][0], qf[qi][0], sacc[qi][st], 0, 0, 0);
            sacc[qi][st] = __builtin_amdgcn_mfma_f32_16x16x32_bf16(kf[st][1], qf[qi][1], sacc[qi][st], 0, 0, 0);
        }
        __builtin_amdgcn_s_setprio(0);

        // ---- V fragments from LDS (A-frag: lane l15 = d row, k = s) ----
        short8 vf[4][2];
        #pragma unroll
        for (int dct = 0; dct < 4; dct++) {
            const int row = dct * 16 + l15;
            #pragma unroll
            for (int half = 0; half < 2; half++) {
                const int slot = ((half << 2) | lhi) ^ rsw;
                vf[dct][half] = *(const short8*)&Vlds[buf][row * 64 + slot * 8];
            }
        }

        // ---- softmax per q-subtile ----
        short8 pf[2][2];
        #pragma unroll
        for (int qi = 0; qi < 2; qi++) {
            const int qb = qbase + qi * 16;
            const int q = qb + l15;
            if (s0 + 63 > qb) {              // diagonal tile: causal mask
                #pragma unroll
                for (int st = 0; st < 4; st++)
                #pragma unroll
                for (int j = 0; j < 4; j++) {
                    int s = s0 + st * 16 + lhi * 4 + j;
                    if (s > q) sacc[qi][st][j] = -1e30f;
                }
            }

            float rmax = sacc[qi][0][0];
            #pragma unroll
            for (int st = 0; st < 4; st++)
            #pragma unroll
            for (int j = 0; j < 4; j++) rmax = fmaxf(rmax, sacc[qi][st][j]);
            rmax = fmaxf(rmax, __shfl_xor(rmax, 16));
            rmax = fmaxf(rmax, __shfl_xor(rmax, 32));

            // T13 defer-max (exp2 domain, P <= 2^8)
            if (!__all(rmax <= m_run[qi] + 8.0f)) {
                float mnew = fmaxf(m_run[qi], rmax);
                float rr = exp2_hw(m_run[qi] - mnew);
                m_run[qi] = mnew;
                l_run[qi] *= rr;
                #pragma unroll
                for (int dct = 0; dct < 4; dct++)
                #pragma unroll
                for (int j = 0; j < 4; j++) oacc[qi][dct][j] *= rr;
            }
            const float mcur = m_run[qi];

            float psum = 0.f;
            unsigned int pk[4][2];
            #pragma unroll
            for (int st = 0; st < 4; st++) {
                float p0 = exp2_hw(sacc[qi][st][0] - mcur);
                float p1 = exp2_hw(sacc[qi][st][1] - mcur);
                float p2 = exp2_hw(sacc[qi][st][2] - mcur);
                float p3 = exp2_hw(sacc[qi][st][3] - mcur);
                psum += (p0 + p1) + (p2 + p3);
                pk[st][0] = cvt_pk_bf16(p0, p1);
                pk[st][1] = cvt_pk_bf16(p2, p3);
            }
            psum += __shfl_xor(psum, 16);
            psum += __shfl_xor(psum, 32);
            l_run[qi] += psum;

            #pragma unroll
            for (int st = 0; st < 4; st++) {
                *(unsigned int*)&plds[wid][l15][st * 16 + lhi * 4 + 0] = pk[st][0];
                *(unsigned int*)&plds[wid][l15][st * 16 + lhi * 4 + 2] = pk[st][1];
            }
            pf[qi][0] = *(const short8*)&plds[wid][l15][lhi * 8];
            pf[qi][1] = *(const short8*)&plds[wid][l15][32 + lhi * 8];
        }

        // ---- PV for both q-subtiles ----
        __builtin_amdgcn_s_setprio(1);
        #pragma unroll
        for (int qi = 0; qi < 2; qi++)
        #pragma unroll
        for (int dct = 0; dct < 4; dct++) {
            oacc[qi][dct] = __builtin_amdgcn_mfma_f32_16x16x32_bf16(vf[dct][0], pf[qi][0], oacc[qi][dct], 0, 0, 0);
            oacc[qi][dct] = __builtin_amdgcn_mfma_f32_16x16x32_bf16(vf[dct][1], pf[qi][1], oacc[qi][dct], 0, 0, 0);
        }
        __builtin_amdgcn_s_setprio(0);

        // staging for t+1 complete + all waves done reading buf before overwrite
        asm volatile("s_waitcnt vmcnt(0)" ::: "memory");
        __syncthreads();
    }

    // ---- epilogue: per-wave O write ----
    #pragma unroll
    for (int qi = 0; qi < 2; qi++) {
        float rl = 1.0f / l_run[qi];
        const int q = qbase + qi * 16 + l15;
        unsigned short* op = O + ((size_t)(b * S_LEN + q) * HQ + h) * HD + lhi * 4;
        #pragma unroll
        for (int dct = 0; dct < 4; dct++) {
            unsigned int w0 = cvt_pk_bf16(oacc[qi][dct][0] * rl, oacc[qi][dct][1] * rl);
            unsigned int w1 = cvt_pk_bf16(oacc[qi][dct][2] * rl, oacc[qi][dct][3] * rl);
            *(unsigned int*)(op + dct * 16)     = w0;
            *(unsigned int*)(op + dct * 16 + 2) = w1;
        }
    }
}

extern "C" void kernel_launch(void* const* d_in, const int* in_sizes, int n_in,
                              void* d_out, int out_size, void* d_ws, size_t ws_size,
                              hipStream_t stream) {
    const float* x    = (const float*)d_in[0];
    const float* wq   = (const float*)d_in[1];
    const float* wk   = (const float*)d_in[2];
    const float* wv   = (const float*)d_in[3];
    const float* wo   = (const float*)d_in[4];
    const float* fcos = (const float*)d_in[5];
    const float* fsin = (const float*)d_in[6];
    float* out = (float*)d_out;

    char* ws = (char*)d_ws;
    unsigned short* xb    = (unsigned short*)(ws);              // 8 MB
    unsigned short* wqkvb = (unsigned short*)(ws + 8388608);    // 3 MB [1536][1024]
    unsigned short* wob   = (unsigned short*)(ws + 11534336);   // 2 MB
    unsigned short* Qb    = (unsigned short*)(ws + 13631488);   // 8 MB
    unsigned short* Kb    = (unsigned short*)(ws + 22020096);   // 2 MB
    unsigned short* Vtb   = (unsigned short*)(ws + 24117248);   // 2 MB
    unsigned short* Ab    = (unsigned short*)(ws + 26214400);   // 8 MB

    cvt_f32_bf16<<<1024, 256, 0, stream>>>(x, xb, 4096 * 1024);
    cvt_weights<<<2560, 256, 0, stream>>>(wq, wk, wv, wo, wqkvb);

    gemm128<1><<<dim3(32, 12), 256, 0, stream>>>(xb, wqkvb, nullptr, Qb, Kb, Vtb,
                                                 fcos, fsin, 1024, 1536);

    flash_attn<<<512, 256, 0, stream>>>(Qb, Kb, Vtb, Ab);

    gemm128<0><<<dim3(32, 8), 256, 0, stream>>>(Ab, wob, out, nullptr, nullptr, nullptr,
                                                nullptr, nullptr, 1024, 1024);
}